// Round 1
// baseline (788.733 us; speedup 1.0000x reference)
//
#include <hip/hip_runtime.h>
#include <cstdint>

typedef unsigned int uint;
typedef unsigned short ushort_t;
typedef unsigned long long ull;

#define B_   16
#define N_   2048
#define S_   512
#define G_   8192       // B_*S_
#define DIN  64
#define DOUT 128
#define K_   32

__device__ __forceinline__ uint bf16b(float f) {
  uint u = __float_as_uint(f);
  return (u + 0x7fffu + ((u >> 16) & 1u)) >> 16;
}
__device__ __forceinline__ float bf2f(uint b) { return __uint_as_float(b << 16); }

// ---------------- FPS: one block per batch, exact fp32 (no FMA contraction) --------
__global__ __launch_bounds__(256) void fps_kernel(const float* __restrict__ coords,
                                                  int* __restrict__ fidx,
                                                  float* __restrict__ out_xyz) {
  int b = blockIdx.x;
  const float* cb = coords + (size_t)b * (N_ * 3);
  __shared__ float sx[N_], sy[N_], sz[N_];
  __shared__ float redv[2][4];
  __shared__ int   redi[2][4];
  int tid = threadIdx.x;
  for (int j = tid; j < N_; j += 256) {
    sx[j] = cb[3 * j]; sy[j] = cb[3 * j + 1]; sz[j] = cb[3 * j + 2];
  }
  __syncthreads();
  float px[8], py[8], pz[8], dist[8];
  int j0 = tid * 8;
#pragma unroll
  for (int i = 0; i < 8; ++i) {
    px[i] = sx[j0 + i]; py[i] = sy[j0 + i]; pz[i] = sz[j0 + i];
    dist[i] = 1e10f;
  }
  int far = 0;
  int lane = tid & 63, wid = tid >> 6;
  for (int s = 0; s < S_; ++s) {
    if (tid == 0) {
      fidx[b * S_ + s] = far;
      int o = (b * S_ + s) * 3;
      out_xyz[o] = sx[far]; out_xyz[o + 1] = sy[far]; out_xyz[o + 2] = sz[far];
    }
    float cx = sx[far], cy = sy[far], cz = sz[far];
    float bestv = -1.f; int bestj = 0;
#pragma unroll
    for (int i = 0; i < 8; ++i) {
      float dx = __fsub_rn(px[i], cx);
      float dy = __fsub_rn(py[i], cy);
      float dz = __fsub_rn(pz[i], cz);
      float d = __fadd_rn(__fadd_rn(__fmul_rn(dx, dx), __fmul_rn(dy, dy)), __fmul_rn(dz, dz));
      float nd = fminf(dist[i], d);
      dist[i] = nd;
      if (nd > bestv) { bestv = nd; bestj = j0 + i; }   // ascending i -> first-index tie-break
    }
#pragma unroll
    for (int off = 32; off > 0; off >>= 1) {
      float ov = __shfl_down(bestv, off, 64);
      int   oj = __shfl_down(bestj, off, 64);
      if (ov > bestv || (ov == bestv && oj < bestj)) { bestv = ov; bestj = oj; }
    }
    int pb = s & 1;
    if (lane == 0) { redv[pb][wid] = bestv; redi[pb][wid] = bestj; }
    __syncthreads();
    float bv = redv[pb][0]; int bj = redi[pb][0];
#pragma unroll
    for (int w = 1; w < 4; ++w) {
      float v = redv[pb][w]; int j = redi[pb][w];
      if (v > bv || (v == bv && j < bj)) { bv = v; bj = j; }
    }
    far = bj;
  }
}

// ---------------- Ball query: one wave per centroid ----------------
__global__ __launch_bounds__(256) void ball_kernel(const float* __restrict__ coords,
                                                   const int* __restrict__ fidx,
                                                   int* __restrict__ gidx) {
  int lane = threadIdx.x & 63;
  int g = __builtin_amdgcn_readfirstlane(blockIdx.x * 4 + (threadIdx.x >> 6));
  int b = g >> 9;
  const float* cb = coords + (size_t)b * (N_ * 3);
  int nf = fidx[g];
  float cx = cb[3 * nf], cy = cb[3 * nf + 1], cz = cb[3 * nf + 2];
  int* out = gidx + g * K_;
  int cnt = 0, first = 0;
  bool hasfirst = false;
  for (int base = 0; base < N_; base += 64) {
    int j = base + lane;
    float dx = __fsub_rn(cb[3 * j], cx);
    float dy = __fsub_rn(cb[3 * j + 1], cy);
    float dz = __fsub_rn(cb[3 * j + 2], cz);
    float d = __fadd_rn(__fadd_rn(__fmul_rn(dx, dx), __fmul_rn(dy, dy)), __fmul_rn(dz, dz));
    bool in = (d <= 0.25f);     // kept iff sqr <= r^2 (ref excludes sqr > r^2)
    ull m = __ballot(in);
    if (in) {
      int pos = cnt + __popcll(m & ((1ull << lane) - 1ull));
      if (pos < K_) out[pos] = j;
    }
    if (!hasfirst && m) { first = base + (__ffsll((long long)m) - 1); hasfirst = true; }
    cnt += __popcll(m);
    if (cnt >= K_) break;
  }
  if (cnt < K_) {
    for (int p = cnt + lane; p < K_; p += 64) out[p] = first;
  }
}

// ---------------- prep: transpose W1,W2; Wdiff for center term ----------------
__global__ __launch_bounds__(256) void prep_kernel(const float* __restrict__ W1,
                                                   const float* __restrict__ W2,
                                                   float* __restrict__ Wt1,
                                                   float* __restrict__ Wt2,
                                                   float* __restrict__ Wd1) {
  int i = blockIdx.x * 256 + threadIdx.x;   // 16384
  int o = i >> 7, c = i & 127;
  float w1 = W1[i];
  Wt1[c * 128 + o] = w1;
  Wt2[c * 128 + o] = W2[i];
  if (c < 64) Wd1[c * 128 + o] = W1[o * 128 + 64 + c] - w1;
}

// ---------------- GEMM1: h1[g,o,k] = sum_c W1[o,c]*xg[c,k] + cterm[o] ----------------
// one wave = one group; lane tile 8o x 8k
__global__ __launch_bounds__(256) void gemm1_kernel(const float* __restrict__ x,
    const int* __restrict__ fidx, const int* __restrict__ gidx,
    const float* __restrict__ Wt1, const float* __restrict__ Wd1,
    ushort_t* __restrict__ h1, float* __restrict__ psum, float* __restrict__ psq) {
  __shared__ float xg[4][DIN * 36];
  __shared__ float sctr[4][DIN];
  __shared__ float scterm[4][DOUT];
  int tid = threadIdx.x;
  int lane = tid & 63, wid = tid >> 6;
  int g = __builtin_amdgcn_readfirstlane(blockIdx.x * 4 + wid);
  int b = g >> 9;
  const float* xb = x + (size_t)b * (DIN * N_);
  int nf = fidx[g];
  float* xgw = xg[wid];
  float* sc = sctr[wid];
  sc[lane] = xb[(size_t)lane * N_ + nf];          // lane = c (0..63)
  int kk = lane & 31, ch = lane >> 5;
  int gik = gidx[g * K_ + kk];
#pragma unroll
  for (int cc = 0; cc < 32; ++cc) {
    int c = ch * 32 + cc;
    xgw[c * 36 + kk] = xb[(size_t)c * N_ + gik];
  }
  // center term: cterm[o] = sum_c (W1[o,64+c]-W1[o,c]) * ctr[c]
#pragma unroll
  for (int half = 0; half < 2; ++half) {
    int oo = lane + half * 64;
    float a = 0.f;
#pragma unroll 8
    for (int c = 0; c < 64; ++c) a = fmaf(Wd1[c * 128 + oo], sc[c], a);
    scterm[wid][oo] = a;
  }
  int ob = (lane & 15) * 8, kb = (lane >> 4) * 8;
  float acc[8][8];
#pragma unroll
  for (int oo = 0; oo < 8; ++oo) {
    float ct = scterm[wid][ob + oo];
#pragma unroll
    for (int k2 = 0; k2 < 8; ++k2) acc[oo][k2] = ct;
  }
  for (int c = 0; c < 64; ++c) {
    float4 w0 = *(const float4*)&Wt1[c * 128 + ob];
    float4 w1 = *(const float4*)&Wt1[c * 128 + ob + 4];
    float4 x0 = *(const float4*)&xgw[c * 36 + kb];
    float4 x1 = *(const float4*)&xgw[c * 36 + kb + 4];
    float wv[8] = {w0.x, w0.y, w0.z, w0.w, w1.x, w1.y, w1.z, w1.w};
    float xv[8] = {x0.x, x0.y, x0.z, x0.w, x1.x, x1.y, x1.z, x1.w};
#pragma unroll
    for (int oo = 0; oo < 8; ++oo)
#pragma unroll
      for (int k2 = 0; k2 < 8; ++k2)
        acc[oo][k2] = fmaf(wv[oo], xv[k2], acc[oo][k2]);
  }
#pragma unroll
  for (int oo = 0; oo < 8; ++oo) {
    float s = 0.f, q = 0.f;
#pragma unroll
    for (int k2 = 0; k2 < 8; ++k2) { float a = acc[oo][k2]; s += a; q = fmaf(a, a, q); }
    s += __shfl_xor(s, 16, 64); s += __shfl_xor(s, 32, 64);
    q += __shfl_xor(q, 16, 64); q += __shfl_xor(q, 32, 64);
    if (kb == 0) { psum[(ob + oo) * G_ + g] = s; psq[(ob + oo) * G_ + g] = q; }
    uint u0 = (bf16b(acc[oo][1]) << 16) | bf16b(acc[oo][0]);
    uint u1 = (bf16b(acc[oo][3]) << 16) | bf16b(acc[oo][2]);
    uint u2 = (bf16b(acc[oo][5]) << 16) | bf16b(acc[oo][4]);
    uint u3 = (bf16b(acc[oo][7]) << 16) | bf16b(acc[oo][6]);
    *(uint4*)(h1 + ((size_t)(g * 128 + ob + oo)) * K_ + kb) = make_uint4(u0, u1, u2, u3);
  }
}

// ---------------- BN finalize: per-channel mean/var -> scale/shift ----------------
__global__ __launch_bounds__(256) void bn_finalize(const float* __restrict__ psum,
    const float* __restrict__ psq, const float* __restrict__ gamma,
    const float* __restrict__ beta, float* __restrict__ bnp) {
  int o = blockIdx.x, tid = threadIdx.x;
  double s = 0.0, q = 0.0;
  for (int g = tid; g < G_; g += 256) { s += (double)psum[o * G_ + g]; q += (double)psq[o * G_ + g]; }
  __shared__ double ss[256], qq[256];
  ss[tid] = s; qq[tid] = q; __syncthreads();
  for (int off = 128; off > 0; off >>= 1) {
    if (tid < off) { ss[tid] += ss[tid + off]; qq[tid] += qq[tid + off]; }
    __syncthreads();
  }
  if (tid == 0) {
    double n = 262144.0;
    double mean = ss[0] / n, var = qq[0] / n - mean * mean;
    float scv = (float)((double)gamma[o] / sqrt(var + 1e-5));
    bnp[2 * o] = scv;
    bnp[2 * o + 1] = (float)((double)beta[o] - mean * (double)scv);
  }
}

// ---------------- GEMM2: h2 = W2 @ relu(bn1(h1)); keep per-(g,o) max/min + stats ----
__global__ __launch_bounds__(256) void gemm2_kernel(const ushort_t* __restrict__ h1,
    const float* __restrict__ Wt2, const float* __restrict__ bnp1,
    float* __restrict__ psum, float* __restrict__ psq,
    float* __restrict__ hmax, float* __restrict__ hmin) {
  __shared__ float rl[4][DOUT * 36];
  int tid = threadIdx.x;
  int lane = tid & 63, wid = tid >> 6;
  int g = __builtin_amdgcn_readfirstlane(blockIdx.x * 4 + wid);
  const uint* hg = (const uint*)(h1 + (size_t)g * (DOUT * K_));
  float* rlw = rl[wid];
#pragma unroll
  for (int t = 0; t < 32; ++t) {
    int i2 = t * 64 + lane;
    uint v = hg[i2];
    int c = i2 >> 4;
    int k = (i2 & 15) * 2;
    float s1 = bnp1[2 * c], t1 = bnp1[2 * c + 1];
    rlw[c * 36 + k]     = fmaxf(fmaf(bf2f(v & 0xffffu), s1, t1), 0.f);
    rlw[c * 36 + k + 1] = fmaxf(fmaf(bf2f(v >> 16), s1, t1), 0.f);
  }
  int ob = (lane & 15) * 8, kb = (lane >> 4) * 8;
  float acc[8][8];
#pragma unroll
  for (int oo = 0; oo < 8; ++oo)
#pragma unroll
    for (int k2 = 0; k2 < 8; ++k2) acc[oo][k2] = 0.f;
  for (int c = 0; c < 128; ++c) {
    float4 w0 = *(const float4*)&Wt2[c * 128 + ob];
    float4 w1 = *(const float4*)&Wt2[c * 128 + ob + 4];
    float4 x0 = *(const float4*)&rlw[c * 36 + kb];
    float4 x1 = *(const float4*)&rlw[c * 36 + kb + 4];
    float wv[8] = {w0.x, w0.y, w0.z, w0.w, w1.x, w1.y, w1.z, w1.w};
    float xv[8] = {x0.x, x0.y, x0.z, x0.w, x1.x, x1.y, x1.z, x1.w};
#pragma unroll
    for (int oo = 0; oo < 8; ++oo)
#pragma unroll
      for (int k2 = 0; k2 < 8; ++k2)
        acc[oo][k2] = fmaf(wv[oo], xv[k2], acc[oo][k2]);
  }
#pragma unroll
  for (int oo = 0; oo < 8; ++oo) {
    float s = 0.f, q = 0.f, mx = -1e30f, mn = 1e30f;
#pragma unroll
    for (int k2 = 0; k2 < 8; ++k2) {
      float a = acc[oo][k2];
      s += a; q = fmaf(a, a, q); mx = fmaxf(mx, a); mn = fminf(mn, a);
    }
    s += __shfl_xor(s, 16, 64); s += __shfl_xor(s, 32, 64);
    q += __shfl_xor(q, 16, 64); q += __shfl_xor(q, 32, 64);
    mx = fmaxf(mx, __shfl_xor(mx, 16, 64)); mx = fmaxf(mx, __shfl_xor(mx, 32, 64));
    mn = fminf(mn, __shfl_xor(mn, 16, 64)); mn = fminf(mn, __shfl_xor(mn, 32, 64));
    if (kb == 0) {
      psum[(ob + oo) * G_ + g] = s; psq[(ob + oo) * G_ + g] = q;
      hmax[(ob + oo) * G_ + g] = mx; hmin[(ob + oo) * G_ + g] = mn;
    }
  }
}

// ---------------- pool: out[b,o,s] = relu(s2 * (s2>=0 ? max : min) + t2) ----------------
__global__ __launch_bounds__(256) void pool_kernel(const float* __restrict__ hmax,
    const float* __restrict__ hmin, const float* __restrict__ bnp2,
    float* __restrict__ out) {
  int i = blockIdx.x * 256 + threadIdx.x;   // 1,048,576 = (b*128+o)*512+s
  int s = i & 511;
  int o = (i >> 9) & 127;
  int b = i >> 16;
  int g = b * 512 + s;
  float scv = bnp2[2 * o], tf = bnp2[2 * o + 1];
  float v = (scv >= 0.f) ? hmax[o * G_ + g] : hmin[o * G_ + g];
  out[i] = fmaxf(fmaf(scv, v, tf), 0.f);
}

extern "C" void kernel_launch(void* const* d_in, const int* in_sizes, int n_in,
                              void* d_out, int out_size, void* d_ws, size_t ws_size,
                              hipStream_t stream) {
  const float* x      = (const float*)d_in[0];
  const float* coords = (const float*)d_in[1];
  const float* W1     = (const float*)d_in[2];
  const float* W2     = (const float*)d_in[3];
  const float* gamma1 = (const float*)d_in[4];
  const float* beta1  = (const float*)d_in[5];
  const float* gamma2 = (const float*)d_in[6];
  const float* beta2  = (const float*)d_in[7];
  float* out = (float*)d_out;
  char* ws = (char*)d_ws;
  ushort_t* h1 = (ushort_t*)(ws);                 // 67,108,864 B
  float* psum1 = (float*)(ws + 67108864);         // 4 MB each below
  float* psq1  = (float*)(ws + 71303168);
  float* psum2 = (float*)(ws + 75497472);
  float* psq2  = (float*)(ws + 79691776);
  float* hmax  = (float*)(ws + 83886080);
  float* hmin  = (float*)(ws + 88080384);
  float* Wt1   = (float*)(ws + 92274688);
  float* Wt2   = (float*)(ws + 92340224);
  float* Wd1   = (float*)(ws + 92405760);
  float* bnp1  = (float*)(ws + 92438528);
  float* bnp2  = (float*)(ws + 92439552);
  int* fidx    = (int*)(ws + 92440576);
  int* gidx    = (int*)(ws + 92473344);           // end 93,521,920 B

  prep_kernel<<<64, 256, 0, stream>>>(W1, W2, Wt1, Wt2, Wd1);
  fps_kernel<<<16, 256, 0, stream>>>(coords, fidx, out);
  ball_kernel<<<2048, 256, 0, stream>>>(coords, fidx, gidx);
  gemm1_kernel<<<2048, 256, 0, stream>>>(x, fidx, gidx, Wt1, Wd1, h1, psum1, psq1);
  bn_finalize<<<128, 256, 0, stream>>>(psum1, psq1, gamma1, beta1, bnp1);
  gemm2_kernel<<<2048, 256, 0, stream>>>(h1, Wt2, bnp1, psum2, psq2, hmax, hmin);
  bn_finalize<<<128, 256, 0, stream>>>(psum2, psq2, gamma2, beta2, bnp2);
  pool_kernel<<<4096, 256, 0, stream>>>(hmax, hmin, bnp2, out + 24576);
}

// Round 3
// 491.134 us; speedup vs baseline: 1.6059x; 1.6059x over previous
//
#include <hip/hip_runtime.h>
#include <cstdint>

typedef unsigned int uint;
typedef unsigned short ushort_t;
typedef unsigned long long ull;

#define B_   16
#define N_   2048
#define S_   512
#define G_   8192       // B_*S_
#define DIN  64
#define DOUT 128
#define K_   32

__device__ __forceinline__ uint bf16b(float f) {
  uint u = __float_as_uint(f);
  return (u + 0x7fffu + ((u >> 16) & 1u)) >> 16;
}
__device__ __forceinline__ float bf2f(uint b) { return __uint_as_float(b << 16); }

// u64 max with one DPP step applied to both halves (bc=1 zero-fill = identity for max)
template<int CTRL, int RM>
__device__ __forceinline__ ull dpp_max_step(ull x) {
  uint lo = (uint)x, hi = (uint)(x >> 32);
  uint nlo = (uint)__builtin_amdgcn_update_dpp((int)lo, (int)lo, CTRL, RM, 0xf, true);
  uint nhi = (uint)__builtin_amdgcn_update_dpp((int)hi, (int)hi, CTRL, RM, 0xf, true);
  ull y = ((ull)nhi << 32) | (ull)nlo;
  return x > y ? x : y;
}

// ---------------- FPS: one block per batch, exact fp32 (no FMA contraction) --------
// 4 waves, 8 pts/thread. Packed (dist_bits<<32 | ~j) u64 argmax: DPP wave reduce
// (VALU-only), one lgkm-only barrier/step, all global writes after the loop.
// NOTE: reference scan emits the PRE-update far (idx[0]==0) -> record at loop top.
__global__ __launch_bounds__(256) void fps_kernel(const float* __restrict__ coords,
                                                  int* __restrict__ fidx,
                                                  float* __restrict__ out_xyz) {
  int b = blockIdx.x;
  const float* cb = coords + (size_t)b * (N_ * 3);
  __shared__ float sx[N_], sy[N_], sz[N_];
  __shared__ ull wcand[2][4];
  __shared__ int sfar[S_];
  int tid = threadIdx.x;
  for (int j = tid; j < N_; j += 256) {
    sx[j] = cb[3 * j]; sy[j] = cb[3 * j + 1]; sz[j] = cb[3 * j + 2];
  }
  __syncthreads();
  float px[8], py[8], pz[8], dist[8];
  uint nidx[8];
  int j0 = tid * 8;
#pragma unroll
  for (int i = 0; i < 8; ++i) {
    px[i] = sx[j0 + i]; py[i] = sy[j0 + i]; pz[i] = sz[j0 + i];
    dist[i] = 1e10f;
    nidx[i] = ~(uint)(j0 + i);     // max(~j) == min(j): first-index tie-break
  }
  int far = 0;
  int lane = tid & 63, wid = tid >> 6;
  for (int s = 0; s < S_; ++s) {
    if (tid == 0) sfar[s] = far;              // PRE-update far (matches jax scan output)
    float cx = sx[far], cy = sy[far], cz = sz[far];
    ull best = 0;
#pragma unroll
    for (int i = 0; i < 8; ++i) {
      float dx = __fsub_rn(px[i], cx);
      float dy = __fsub_rn(py[i], cy);
      float dz = __fsub_rn(pz[i], cz);
      float d = __fadd_rn(__fadd_rn(__fmul_rn(dx, dx), __fmul_rn(dy, dy)), __fmul_rn(dz, dz));
      float nd = fminf(dist[i], d);
      dist[i] = nd;
      ull p = ((ull)__float_as_uint(nd) << 32) | (ull)nidx[i];
      best = best > p ? best : p;
    }
    // wave64 max-reduce, result lands in lane 63 (VALU-only DPP chain)
    best = dpp_max_step<0x111, 0xf>(best);   // row_shr:1
    best = dpp_max_step<0x112, 0xf>(best);   // row_shr:2
    best = dpp_max_step<0x114, 0xf>(best);   // row_shr:4
    best = dpp_max_step<0x118, 0xf>(best);   // row_shr:8
    best = dpp_max_step<0x142, 0xa>(best);   // row_bcast:15 -> rows 1,3
    best = dpp_max_step<0x143, 0xc>(best);   // row_bcast:31 -> rows 2,3
    int pb = s & 1;
    if (lane == 63) wcand[pb][wid] = best;
    __syncthreads();                          // lgkm-only: no global ops in flight
    ull c0 = wcand[pb][0], c1 = wcand[pb][1], c2 = wcand[pb][2], c3 = wcand[pb][3];
    ull m01 = c0 > c1 ? c0 : c1;
    ull m23 = c2 > c3 ? c2 : c3;
    ull mall = m01 > m23 ? m01 : m23;
    far = (int)(~(uint)mall);
  }
  __syncthreads();
  for (int s2 = tid; s2 < S_; s2 += 256) {
    int f = sfar[s2];
    fidx[b * S_ + s2] = f;
    int o = (b * S_ + s2) * 3;
    out_xyz[o] = sx[f]; out_xyz[o + 1] = sy[f]; out_xyz[o + 2] = sz[f];
  }
}

// ---------------- Ball query: one wave per centroid ----------------
__global__ __launch_bounds__(256) void ball_kernel(const float* __restrict__ coords,
                                                   const int* __restrict__ fidx,
                                                   int* __restrict__ gidx) {
  int lane = threadIdx.x & 63;
  int g = __builtin_amdgcn_readfirstlane(blockIdx.x * 4 + (threadIdx.x >> 6));
  int b = g >> 9;
  const float* cb = coords + (size_t)b * (N_ * 3);
  int nf = fidx[g];
  float cx = cb[3 * nf], cy = cb[3 * nf + 1], cz = cb[3 * nf + 2];
  int* out = gidx + g * K_;
  int cnt = 0, first = 0;
  bool hasfirst = false;
  for (int base = 0; base < N_; base += 64) {
    int j = base + lane;
    float dx = __fsub_rn(cb[3 * j], cx);
    float dy = __fsub_rn(cb[3 * j + 1], cy);
    float dz = __fsub_rn(cb[3 * j + 2], cz);
    float d = __fadd_rn(__fadd_rn(__fmul_rn(dx, dx), __fmul_rn(dy, dy)), __fmul_rn(dz, dz));
    bool in = (d <= 0.25f);     // kept iff sqr <= r^2 (ref excludes sqr > r^2)
    ull m = __ballot(in);
    if (in) {
      int pos = cnt + __popcll(m & ((1ull << lane) - 1ull));
      if (pos < K_) out[pos] = j;
    }
    if (!hasfirst && m) { first = base + (__ffsll((long long)m) - 1); hasfirst = true; }
    cnt += __popcll(m);
    if (cnt >= K_) break;
  }
  if (cnt < K_) {
    for (int p = cnt + lane; p < K_; p += 64) out[p] = first;
  }
}

// ---------------- prep: transpose W1,W2; Wdiff for center term ----------------
__global__ __launch_bounds__(256) void prep_kernel(const float* __restrict__ W1,
                                                   const float* __restrict__ W2,
                                                   float* __restrict__ Wt1,
                                                   float* __restrict__ Wt2,
                                                   float* __restrict__ Wd1) {
  int i = blockIdx.x * 256 + threadIdx.x;   // 16384
  int o = i >> 7, c = i & 127;
  float w1 = W1[i];
  Wt1[c * 128 + o] = w1;
  Wt2[c * 128 + o] = W2[i];
  if (c < 64) Wd1[c * 128 + o] = W1[o * 128 + 64 + c] - w1;
}

// ---------------- GEMM1: h1[g,o,k] = sum_c W1[o,c]*xg[c,k] + cterm[o] ----------------
// one wave = one group; lane tile 8o x 8k
__global__ __launch_bounds__(256) void gemm1_kernel(const float* __restrict__ x,
    const int* __restrict__ fidx, const int* __restrict__ gidx,
    const float* __restrict__ Wt1, const float* __restrict__ Wd1,
    ushort_t* __restrict__ h1, float* __restrict__ psum, float* __restrict__ psq) {
  __shared__ float xg[4][DIN * 36];
  __shared__ float sctr[4][DIN];
  __shared__ float scterm[4][DOUT];
  int tid = threadIdx.x;
  int lane = tid & 63, wid = tid >> 6;
  int g = __builtin_amdgcn_readfirstlane(blockIdx.x * 4 + wid);
  int b = g >> 9;
  const float* xb = x + (size_t)b * (DIN * N_);
  int nf = fidx[g];
  float* xgw = xg[wid];
  float* sc = sctr[wid];
  sc[lane] = xb[(size_t)lane * N_ + nf];          // lane = c (0..63)
  int kk = lane & 31, ch = lane >> 5;
  int gik = gidx[g * K_ + kk];
#pragma unroll
  for (int cc = 0; cc < 32; ++cc) {
    int c = ch * 32 + cc;
    xgw[c * 36 + kk] = xb[(size_t)c * N_ + gik];
  }
  // center term: cterm[o] = sum_c (W1[o,64+c]-W1[o,c]) * ctr[c]
#pragma unroll
  for (int half = 0; half < 2; ++half) {
    int oo = lane + half * 64;
    float a = 0.f;
#pragma unroll 8
    for (int c = 0; c < 64; ++c) a = fmaf(Wd1[c * 128 + oo], sc[c], a);
    scterm[wid][oo] = a;
  }
  int ob = (lane & 15) * 8, kb = (lane >> 4) * 8;
  float acc[8][8];
#pragma unroll
  for (int oo = 0; oo < 8; ++oo) {
    float ct = scterm[wid][ob + oo];
#pragma unroll
    for (int k2 = 0; k2 < 8; ++k2) acc[oo][k2] = ct;
  }
  for (int c = 0; c < 64; ++c) {
    float4 w0 = *(const float4*)&Wt1[c * 128 + ob];
    float4 w1 = *(const float4*)&Wt1[c * 128 + ob + 4];
    float4 x0 = *(const float4*)&xgw[c * 36 + kb];
    float4 x1 = *(const float4*)&xgw[c * 36 + kb + 4];
    float wv[8] = {w0.x, w0.y, w0.z, w0.w, w1.x, w1.y, w1.z, w1.w};
    float xv[8] = {x0.x, x0.y, x0.z, x0.w, x1.x, x1.y, x1.z, x1.w};
#pragma unroll
    for (int oo = 0; oo < 8; ++oo)
#pragma unroll
      for (int k2 = 0; k2 < 8; ++k2)
        acc[oo][k2] = fmaf(wv[oo], xv[k2], acc[oo][k2]);
  }
#pragma unroll
  for (int oo = 0; oo < 8; ++oo) {
    float s = 0.f, q = 0.f;
#pragma unroll
    for (int k2 = 0; k2 < 8; ++k2) { float a = acc[oo][k2]; s += a; q = fmaf(a, a, q); }
    s += __shfl_xor(s, 16, 64); s += __shfl_xor(s, 32, 64);
    q += __shfl_xor(q, 16, 64); q += __shfl_xor(q, 32, 64);
    if (kb == 0) { psum[(ob + oo) * G_ + g] = s; psq[(ob + oo) * G_ + g] = q; }
    uint u0 = (bf16b(acc[oo][1]) << 16) | bf16b(acc[oo][0]);
    uint u1 = (bf16b(acc[oo][3]) << 16) | bf16b(acc[oo][2]);
    uint u2 = (bf16b(acc[oo][5]) << 16) | bf16b(acc[oo][4]);
    uint u3 = (bf16b(acc[oo][7]) << 16) | bf16b(acc[oo][6]);
    *(uint4*)(h1 + ((size_t)(g * 128 + ob + oo)) * K_ + kb) = make_uint4(u0, u1, u2, u3);
  }
}

// ---------------- BN finalize: per-channel mean/var -> scale/shift ----------------
__global__ __launch_bounds__(256) void bn_finalize(const float* __restrict__ psum,
    const float* __restrict__ psq, const float* __restrict__ gamma,
    const float* __restrict__ beta, float* __restrict__ bnp) {
  int o = blockIdx.x, tid = threadIdx.x;
  double s = 0.0, q = 0.0;
  for (int g = tid; g < G_; g += 256) { s += (double)psum[o * G_ + g]; q += (double)psq[o * G_ + g]; }
  __shared__ double ss[256], qq[256];
  ss[tid] = s; qq[tid] = q; __syncthreads();
  for (int off = 128; off > 0; off >>= 1) {
    if (tid < off) { ss[tid] += ss[tid + off]; qq[tid] += qq[tid + off]; }
    __syncthreads();
  }
  if (tid == 0) {
    double n = 262144.0;
    double mean = ss[0] / n, var = qq[0] / n - mean * mean;
    float scv = (float)((double)gamma[o] / sqrt(var + 1e-5));
    bnp[2 * o] = scv;
    bnp[2 * o + 1] = (float)((double)beta[o] - mean * (double)scv);
  }
}

// ---------------- GEMM2: h2 = W2 @ relu(bn1(h1)); keep per-(g,o) max/min + stats ----
__global__ __launch_bounds__(256) void gemm2_kernel(const ushort_t* __restrict__ h1,
    const float* __restrict__ Wt2, const float* __restrict__ bnp1,
    float* __restrict__ psum, float* __restrict__ psq,
    float* __restrict__ hmax, float* __restrict__ hmin) {
  __shared__ float rl[4][DOUT * 36];
  int tid = threadIdx.x;
  int lane = tid & 63, wid = tid >> 6;
  int g = __builtin_amdgcn_readfirstlane(blockIdx.x * 4 + wid);
  const uint* hg = (const uint*)(h1 + (size_t)g * (DOUT * K_));
  float* rlw = rl[wid];
#pragma unroll
  for (int t = 0; t < 32; ++t) {
    int i2 = t * 64 + lane;
    uint v = hg[i2];
    int c = i2 >> 4;
    int k = (i2 & 15) * 2;
    float s1 = bnp1[2 * c], t1 = bnp1[2 * c + 1];
    rlw[c * 36 + k]     = fmaxf(fmaf(bf2f(v & 0xffffu), s1, t1), 0.f);
    rlw[c * 36 + k + 1] = fmaxf(fmaf(bf2f(v >> 16), s1, t1), 0.f);
  }
  int ob = (lane & 15) * 8, kb = (lane >> 4) * 8;
  float acc[8][8];
#pragma unroll
  for (int oo = 0; oo < 8; ++oo)
#pragma unroll
    for (int k2 = 0; k2 < 8; ++k2) acc[oo][k2] = 0.f;
  for (int c = 0; c < 128; ++c) {
    float4 w0 = *(const float4*)&Wt2[c * 128 + ob];
    float4 w1 = *(const float4*)&Wt2[c * 128 + ob + 4];
    float4 x0 = *(const float4*)&rlw[c * 36 + kb];
    float4 x1 = *(const float4*)&rlw[c * 36 + kb + 4];
    float wv[8] = {w0.x, w0.y, w0.z, w0.w, w1.x, w1.y, w1.z, w1.w};
    float xv[8] = {x0.x, x0.y, x0.z, x0.w, x1.x, x1.y, x1.z, x1.w};
#pragma unroll
    for (int oo = 0; oo < 8; ++oo)
#pragma unroll
      for (int k2 = 0; k2 < 8; ++k2)
        acc[oo][k2] = fmaf(wv[oo], xv[k2], acc[oo][k2]);
  }
#pragma unroll
  for (int oo = 0; oo < 8; ++oo) {
    float s = 0.f, q = 0.f, mx = -1e30f, mn = 1e30f;
#pragma unroll
    for (int k2 = 0; k2 < 8; ++k2) {
      float a = acc[oo][k2];
      s += a; q = fmaf(a, a, q); mx = fmaxf(mx, a); mn = fminf(mn, a);
    }
    s += __shfl_xor(s, 16, 64); s += __shfl_xor(s, 32, 64);
    q += __shfl_xor(q, 16, 64); q += __shfl_xor(q, 32, 64);
    mx = fmaxf(mx, __shfl_xor(mx, 16, 64)); mx = fmaxf(mx, __shfl_xor(mx, 32, 64));
    mn = fminf(mn, __shfl_xor(mn, 16, 64)); mn = fminf(mn, __shfl_xor(mn, 32, 64));
    if (kb == 0) {
      psum[(ob + oo) * G_ + g] = s; psq[(ob + oo) * G_ + g] = q;
      hmax[(ob + oo) * G_ + g] = mx; hmin[(ob + oo) * G_ + g] = mn;
    }
  }
}

// ---------------- pool: out[b,o,s] = relu(s2 * (s2>=0 ? max : min) + t2) ----------------
__global__ __launch_bounds__(256) void pool_kernel(const float* __restrict__ hmax,
    const float* __restrict__ hmin, const float* __restrict__ bnp2,
    float* __restrict__ out) {
  int i = blockIdx.x * 256 + threadIdx.x;   // 1,048,576 = (b*128+o)*512+s
  int s = i & 511;
  int o = (i >> 9) & 127;
  int b = i >> 16;
  int g = b * 512 + s;
  float scv = bnp2[2 * o], tf = bnp2[2 * o + 1];
  float v = (scv >= 0.f) ? hmax[o * G_ + g] : hmin[o * G_ + g];
  out[i] = fmaxf(fmaf(scv, v, tf), 0.f);
}

extern "C" void kernel_launch(void* const* d_in, const int* in_sizes, int n_in,
                              void* d_out, int out_size, void* d_ws, size_t ws_size,
                              hipStream_t stream) {
  const float* x      = (const float*)d_in[0];
  const float* coords = (const float*)d_in[1];
  const float* W1     = (const float*)d_in[2];
  const float* W2     = (const float*)d_in[3];
  const float* gamma1 = (const float*)d_in[4];
  const float* beta1  = (const float*)d_in[5];
  const float* gamma2 = (const float*)d_in[6];
  const float* beta2  = (const float*)d_in[7];
  float* out = (float*)d_out;
  char* ws = (char*)d_ws;
  ushort_t* h1 = (ushort_t*)(ws);                 // 67,108,864 B
  float* psum1 = (float*)(ws + 67108864);         // 4 MB each below
  float* psq1  = (float*)(ws + 71303168);
  float* psum2 = (float*)(ws + 75497472);
  float* psq2  = (float*)(ws + 79691776);
  float* hmax  = (float*)(ws + 83886080);
  float* hmin  = (float*)(ws + 88080384);
  float* Wt1   = (float*)(ws + 92274688);
  float* Wt2   = (float*)(ws + 92340224);
  float* Wd1   = (float*)(ws + 92405760);
  float* bnp1  = (float*)(ws + 92438528);
  float* bnp2  = (float*)(ws + 92439552);
  int* fidx    = (int*)(ws + 92440576);
  int* gidx    = (int*)(ws + 92473344);           // end 93,521,920 B

  prep_kernel<<<64, 256, 0, stream>>>(W1, W2, Wt1, Wt2, Wd1);
  fps_kernel<<<16, 256, 0, stream>>>(coords, fidx, out);
  ball_kernel<<<2048, 256, 0, stream>>>(coords, fidx, gidx);
  gemm1_kernel<<<2048, 256, 0, stream>>>(x, fidx, gidx, Wt1, Wd1, h1, psum1, psq1);
  bn_finalize<<<128, 256, 0, stream>>>(psum1, psq1, gamma1, beta1, bnp1);
  gemm2_kernel<<<2048, 256, 0, stream>>>(h1, Wt2, bnp1, psum2, psq2, hmax, hmin);
  bn_finalize<<<128, 256, 0, stream>>>(psum2, psq2, gamma2, beta2, bnp2);
  pool_kernel<<<4096, 256, 0, stream>>>(hmax, hmin, bnp2, out + 24576);
}

// Round 4
// 465.905 us; speedup vs baseline: 1.6929x; 1.0542x over previous
//
#include <hip/hip_runtime.h>
#include <cstdint>

typedef unsigned int uint;
typedef unsigned short ushort_t;
typedef unsigned long long ull;
typedef __attribute__((ext_vector_type(8))) short bf16x8;
typedef __attribute__((ext_vector_type(4))) float f32x4;

#define B_   16
#define N_   2048
#define S_   512
#define G_   8192       // B_*S_
#define DIN  64
#define DOUT 128
#define K_   32
#define ATS  136        // actT row stride in bf16 (272B = 17*16 -> aligned, conflict-free)

__device__ __forceinline__ uint bf16b(float f) {
  uint u = __float_as_uint(f);
  return (u + 0x7fffu + ((u >> 16) & 1u)) >> 16;
}
__device__ __forceinline__ float bf2f(uint b) { return __uint_as_float(b << 16); }

// u64 max with one DPP step applied to both halves (bc=1 zero-fill = identity for max)
template<int CTRL, int RM>
__device__ __forceinline__ ull dpp_max_step(ull x) {
  uint lo = (uint)x, hi = (uint)(x >> 32);
  uint nlo = (uint)__builtin_amdgcn_update_dpp((int)lo, (int)lo, CTRL, RM, 0xf, true);
  uint nhi = (uint)__builtin_amdgcn_update_dpp((int)hi, (int)hi, CTRL, RM, 0xf, true);
  ull y = ((ull)nhi << 32) | (ull)nlo;
  return x > y ? x : y;
}

// ---------------- FPS: one block/batch, 4 waves, 8 pts/thread, exact fp32 ----------
// Key-only DPP reduce -> readlane(63) -> winner lane writes {key,coords} slot ->
// barrier -> 4-slot tree select yields far AND center coords in regs (no LDS re-read).
// Reference scan emits PRE-update far (idx[0]==0) -> record at loop top.
__global__ __launch_bounds__(256) void fps_kernel(const float* __restrict__ coords,
                                                  int* __restrict__ fidx,
                                                  float* __restrict__ out_xyz) {
  int b = blockIdx.x;
  const float* cb = coords + (size_t)b * (N_ * 3);
  __shared__ ull    skey[2][4];
  __shared__ float4 scand[2][4];
  __shared__ int    sfar[S_];
  __shared__ float4 scoord[S_];
  int tid = threadIdx.x, wid = tid >> 6;
  float px[8], py[8], pz[8], dist[8];
  uint nidx[8];
  int j0 = tid * 8;
#pragma unroll
  for (int i = 0; i < 8; ++i) {
    px[i] = cb[3 * (j0 + i)]; py[i] = cb[3 * (j0 + i) + 1]; pz[i] = cb[3 * (j0 + i) + 2];
    dist[i] = 1e10f;
    nidx[i] = ~(uint)(j0 + i);     // max(~j) == min(j): first-index tie-break
  }
  float cx = cb[0], cy = cb[1], cz = cb[2];
  uint far = 0;
  for (int s = 0; s < S_; ++s) {
    if (tid == 0) { sfar[s] = (int)far; scoord[s] = make_float4(cx, cy, cz, 0.f); }
    ull best = 0;
#pragma unroll
    for (int i = 0; i < 8; ++i) {
      float dx = __fsub_rn(px[i], cx);
      float dy = __fsub_rn(py[i], cy);
      float dz = __fsub_rn(pz[i], cz);
      float d = __fadd_rn(__fadd_rn(__fmul_rn(dx, dx), __fmul_rn(dy, dy)), __fmul_rn(dz, dz));
      float nd = fminf(dist[i], d);
      dist[i] = nd;
      ull p = ((ull)__float_as_uint(nd) << 32) | (ull)nidx[i];
      best = best > p ? best : p;
    }
    // wave64 max-reduce, result lands in lane 63 (VALU-only DPP chain)
    best = dpp_max_step<0x111, 0xf>(best);   // row_shr:1
    best = dpp_max_step<0x112, 0xf>(best);   // row_shr:2
    best = dpp_max_step<0x114, 0xf>(best);   // row_shr:4
    best = dpp_max_step<0x118, 0xf>(best);   // row_shr:8
    best = dpp_max_step<0x142, 0xa>(best);   // row_bcast:15 -> rows 1,3
    best = dpp_max_step<0x143, 0xc>(best);   // row_bcast:31 -> rows 2,3
    uint khi = (uint)__builtin_amdgcn_readlane((int)(best >> 32), 63);
    uint klo = (uint)__builtin_amdgcn_readlane((int)(best & 0xffffffffull), 63);
    uint jwin = ~klo;                          // this wave's winner point index
    int pb = s & 1;
    if (tid == (int)(jwin >> 3)) {             // exactly one lane per wave
      int iw = (int)(jwin & 7u);
      float a0 = (iw & 1) ? px[1] : px[0], a1 = (iw & 1) ? px[3] : px[2];
      float a2 = (iw & 1) ? px[5] : px[4], a3 = (iw & 1) ? px[7] : px[6];
      float b0 = (iw & 2) ? a1 : a0, b1 = (iw & 2) ? a3 : a2;
      float wx = (iw & 4) ? b1 : b0;
      a0 = (iw & 1) ? py[1] : py[0]; a1 = (iw & 1) ? py[3] : py[2];
      a2 = (iw & 1) ? py[5] : py[4]; a3 = (iw & 1) ? py[7] : py[6];
      b0 = (iw & 2) ? a1 : a0; b1 = (iw & 2) ? a3 : a2;
      float wy = (iw & 4) ? b1 : b0;
      a0 = (iw & 1) ? pz[1] : pz[0]; a1 = (iw & 1) ? pz[3] : pz[2];
      a2 = (iw & 1) ? pz[5] : pz[4]; a3 = (iw & 1) ? pz[7] : pz[6];
      b0 = (iw & 2) ? a1 : a0; b1 = (iw & 2) ? a3 : a2;
      float wz = (iw & 4) ? b1 : b0;
      skey[pb][wid] = ((ull)khi << 32) | (ull)klo;
      scand[pb][wid] = make_float4(wx, wy, wz, 0.f);
    }
    __syncthreads();                           // lgkm-only: no global ops in flight
    ull k0 = skey[pb][0], k1 = skey[pb][1], k2 = skey[pb][2], k3 = skey[pb][3];
    float4 c0 = scand[pb][0], c1 = scand[pb][1], c2 = scand[pb][2], c3 = scand[pb][3];
    bool t01 = k0 > k1, t23 = k2 > k3;
    ull ka = t01 ? k0 : k1;  float4 ca = t01 ? c0 : c1;
    ull kb = t23 ? k2 : k3;  float4 cb4 = t23 ? c2 : c3;
    bool tw = ka > kb;
    ull kw = tw ? ka : kb;   float4 cw = tw ? ca : cb4;
    far = ~(uint)kw;
    cx = cw.x; cy = cw.y; cz = cw.z;
  }
  __syncthreads();
  for (int s2 = tid; s2 < S_; s2 += 256) {
    fidx[b * S_ + s2] = sfar[s2];
    float4 c4 = scoord[s2];
    int o = (b * S_ + s2) * 3;
    out_xyz[o] = c4.x; out_xyz[o + 1] = c4.y; out_xyz[o + 2] = c4.z;
  }
}

// ---------------- Ball query: one wave per centroid ----------------
__global__ __launch_bounds__(256) void ball_kernel(const float* __restrict__ coords,
                                                   const int* __restrict__ fidx,
                                                   int* __restrict__ gidx) {
  int lane = threadIdx.x & 63;
  int g = __builtin_amdgcn_readfirstlane(blockIdx.x * 4 + (threadIdx.x >> 6));
  int b = g >> 9;
  const float* cb = coords + (size_t)b * (N_ * 3);
  int nf = fidx[g];
  float cx = cb[3 * nf], cy = cb[3 * nf + 1], cz = cb[3 * nf + 2];
  int* out = gidx + g * K_;
  int cnt = 0, first = 0;
  bool hasfirst = false;
  for (int base = 0; base < N_; base += 64) {
    int j = base + lane;
    float dx = __fsub_rn(cb[3 * j], cx);
    float dy = __fsub_rn(cb[3 * j + 1], cy);
    float dz = __fsub_rn(cb[3 * j + 2], cz);
    float d = __fadd_rn(__fadd_rn(__fmul_rn(dx, dx), __fmul_rn(dy, dy)), __fmul_rn(dz, dz));
    bool in = (d <= 0.25f);     // kept iff sqr <= r^2 (ref excludes sqr > r^2)
    ull m = __ballot(in);
    if (in) {
      int pos = cnt + __popcll(m & ((1ull << lane) - 1ull));
      if (pos < K_) out[pos] = j;
    }
    if (!hasfirst && m) { first = base + (__ffsll((long long)m) - 1); hasfirst = true; }
    cnt += __popcll(m);
    if (cnt >= K_) break;
  }
  if (cnt < K_) {
    for (int p = cnt + lane; p < K_; p += 64) out[p] = first;
  }
}

// ---------------- prep: Wt1 (transposed), Wd1 (center-diff), Bpack2 (B-frag W2) ----
__global__ __launch_bounds__(256) void prep_kernel(const float* __restrict__ W1,
                                                   const float* __restrict__ W2,
                                                   float* __restrict__ Wt1,
                                                   float* __restrict__ Wd1,
                                                   ushort_t* __restrict__ Bp2) {
  int i = blockIdx.x * 256 + threadIdx.x;   // 16384
  int o = i >> 7, c = i & 127;
  float w1 = W1[i];
  Wt1[c * 128 + o] = w1;
  if (c < 64) Wd1[c * 128 + o] = W1[o * 128 + 64 + c] - w1;
  // B-fragment packing for mfma_f32_16x16x32_bf16: B[k=c][n=o], lane l holds
  // B[kc*32+(l>>4)*8+j][nt*16+(l&15)]
  int j2 = i & 7, l = (i >> 3) & 63, kc = (i >> 9) & 3, nt = i >> 11;
  int o2 = nt * 16 + (l & 15);
  int c2 = kc * 32 + ((l >> 4) * 8) + j2;
  Bp2[i] = (ushort_t)bf16b(W2[o2 * 128 + c2]);
}

// ---------------- GEMM1 (fp32): h1T[g][k][c] = sum W1a[c?]... + cterm ----------------
// one wave = one group; lane tile 8o x 8k; OUTPUT now transposed: h1T[g][k][o->c]
__global__ __launch_bounds__(256) void gemm1_kernel(const float* __restrict__ x,
    const int* __restrict__ fidx, const int* __restrict__ gidx,
    const float* __restrict__ Wt1, const float* __restrict__ Wd1,
    ushort_t* __restrict__ h1T, float* __restrict__ psum, float* __restrict__ psq) {
  __shared__ float xg[4][DIN * 36];
  __shared__ float sctr[4][DIN];
  __shared__ float scterm[4][DOUT];
  int tid = threadIdx.x;
  int lane = tid & 63, wid = tid >> 6;
  int g = __builtin_amdgcn_readfirstlane(blockIdx.x * 4 + wid);
  int b = g >> 9;
  const float* xb = x + (size_t)b * (DIN * N_);
  int nf = fidx[g];
  float* xgw = xg[wid];
  float* sc = sctr[wid];
  sc[lane] = xb[(size_t)lane * N_ + nf];          // lane = c (0..63)
  int kk = lane & 31, ch = lane >> 5;
  int gik = gidx[g * K_ + kk];
#pragma unroll
  for (int cc = 0; cc < 32; ++cc) {
    int c = ch * 32 + cc;
    xgw[c * 36 + kk] = xb[(size_t)c * N_ + gik];
  }
  // center term: cterm[o] = sum_c (W1[o,64+c]-W1[o,c]) * ctr[c]
#pragma unroll
  for (int half = 0; half < 2; ++half) {
    int oo = lane + half * 64;
    float a = 0.f;
#pragma unroll 8
    for (int c = 0; c < 64; ++c) a = fmaf(Wd1[c * 128 + oo], sc[c], a);
    scterm[wid][oo] = a;
  }
  int ob = (lane & 15) * 8, kb = (lane >> 4) * 8;
  float acc[8][8];
#pragma unroll
  for (int oo = 0; oo < 8; ++oo) {
    float ct = scterm[wid][ob + oo];
#pragma unroll
    for (int k2 = 0; k2 < 8; ++k2) acc[oo][k2] = ct;
  }
  for (int c = 0; c < 64; ++c) {
    float4 w0 = *(const float4*)&Wt1[c * 128 + ob];
    float4 w1 = *(const float4*)&Wt1[c * 128 + ob + 4];
    float4 x0 = *(const float4*)&xgw[c * 36 + kb];
    float4 x1 = *(const float4*)&xgw[c * 36 + kb + 4];
    float wv[8] = {w0.x, w0.y, w0.z, w0.w, w1.x, w1.y, w1.z, w1.w};
    float xv[8] = {x0.x, x0.y, x0.z, x0.w, x1.x, x1.y, x1.z, x1.w};
#pragma unroll
    for (int oo = 0; oo < 8; ++oo)
#pragma unroll
      for (int k2 = 0; k2 < 8; ++k2)
        acc[oo][k2] = fmaf(wv[oo], xv[k2], acc[oo][k2]);
  }
#pragma unroll
  for (int oo = 0; oo < 8; ++oo) {
    float s = 0.f, q = 0.f;
#pragma unroll
    for (int k2 = 0; k2 < 8; ++k2) { float a = acc[oo][k2]; s += a; q = fmaf(a, a, q); }
    s += __shfl_xor(s, 16, 64); s += __shfl_xor(s, 32, 64);
    q += __shfl_xor(q, 16, 64); q += __shfl_xor(q, 32, 64);
    if (kb == 0) { psum[(ob + oo) * G_ + g] = s; psq[(ob + oo) * G_ + g] = q; }
  }
  // transposed store: h1T[g][k][c], c contiguous (coalesced 256B per k2 across lanes)
#pragma unroll
  for (int k2 = 0; k2 < 8; ++k2) {
    uint u0 = (bf16b(acc[1][k2]) << 16) | bf16b(acc[0][k2]);
    uint u1 = (bf16b(acc[3][k2]) << 16) | bf16b(acc[2][k2]);
    uint u2 = (bf16b(acc[5][k2]) << 16) | bf16b(acc[4][k2]);
    uint u3 = (bf16b(acc[7][k2]) << 16) | bf16b(acc[6][k2]);
    *(uint4*)(h1T + (size_t)g * 4096 + (kb + k2) * 128 + ob) = make_uint4(u0, u1, u2, u3);
  }
}

// ---------------- BN finalize: per-channel mean/var -> scale/shift ----------------
__global__ __launch_bounds__(256) void bn_finalize(const float* __restrict__ psum,
    const float* __restrict__ psq, const float* __restrict__ gamma,
    const float* __restrict__ beta, float* __restrict__ bnp) {
  int o = blockIdx.x, tid = threadIdx.x;
  double s = 0.0, q = 0.0;
  for (int g = tid; g < G_; g += 256) { s += (double)psum[o * G_ + g]; q += (double)psq[o * G_ + g]; }
  __shared__ double ss[256], qq[256];
  ss[tid] = s; qq[tid] = q; __syncthreads();
  for (int off = 128; off > 0; off >>= 1) {
    if (tid < off) { ss[tid] += ss[tid + off]; qq[tid] += qq[tid + off]; }
    __syncthreads();
  }
  if (tid == 0) {
    double n = 262144.0;
    double mean = ss[0] / n, var = qq[0] / n - mean * mean;
    float scv = (float)((double)gamma[o] / sqrt(var + 1e-5));
    bnp[2 * o] = scv;
    bnp[2 * o + 1] = (float)((double)beta[o] - mean * (double)scv);
  }
}

// ---------------- GEMM2 (MFMA bf16): CT layout D[k][o], per-(g,o) stats ----------
// A[m=k][kk=c] from LDS actT (staged relu(bn1(h1T)) bf16), B[c][o] = Bpack2.
__global__ __launch_bounds__(256) void gemm2_kernel(const ushort_t* __restrict__ h1T,
    const ushort_t* __restrict__ Bp2, const float* __restrict__ bnp1,
    float* __restrict__ psum, float* __restrict__ psq,
    float* __restrict__ hmax, float* __restrict__ hmin) {
  __shared__ ushort_t actT[4][32 * ATS];
  int tid = threadIdx.x;
  int lane = tid & 63, wid = tid >> 6;
  int g = __builtin_amdgcn_readfirstlane(blockIdx.x * 4 + wid);
  ushort_t* aw = actT[wid];
  // bn params for this lane's 8 c-columns (c0 fixed per lane)
  int c0 = (lane & 15) * 8;
  float s1[8], t1[8];
#pragma unroll
  for (int jj = 0; jj < 8; ++jj) { s1[jj] = bnp1[2 * (c0 + jj)]; t1[jj] = bnp1[2 * (c0 + jj) + 1]; }
  const uint4* src = (const uint4*)(h1T + (size_t)g * 4096);
#pragma unroll
  for (int t = 0; t < 8; ++t) {
    int idx = t * 64 + lane;           // uint4 index; k = idx>>4, c-block = (idx&15)*8
    uint4 v = src[idx];
    int k = idx >> 4;
    uint w[4] = {v.x, v.y, v.z, v.w};
    uint o4[4];
#pragma unroll
    for (int p2 = 0; p2 < 4; ++p2) {
      float a0 = fmaxf(fmaf(bf2f(w[p2] & 0xffffu), s1[2 * p2], t1[2 * p2]), 0.f);
      float a1 = fmaxf(fmaf(bf2f(w[p2] >> 16), s1[2 * p2 + 1], t1[2 * p2 + 1]), 0.f);
      o4[p2] = (bf16b(a1) << 16) | bf16b(a0);
    }
    *(uint4*)(aw + k * ATS + c0) = make_uint4(o4[0], o4[1], o4[2], o4[3]);
  }
  __syncthreads();
  f32x4 acc[2][8];
#pragma unroll
  for (int mt = 0; mt < 2; ++mt)
#pragma unroll
    for (int nt = 0; nt < 8; ++nt) acc[mt][nt] = (f32x4){0.f, 0.f, 0.f, 0.f};
#pragma unroll
  for (int kc = 0; kc < 4; ++kc) {
    bf16x8 afrag[2];
#pragma unroll
    for (int mt = 0; mt < 2; ++mt)
      afrag[mt] = *(const bf16x8*)(aw + (mt * 16 + (lane & 15)) * ATS + kc * 32 + (lane >> 4) * 8);
#pragma unroll
    for (int nt = 0; nt < 8; ++nt) {
      bf16x8 bfrag = *(const bf16x8*)(Bp2 + ((nt * 4 + kc) * 64 + lane) * 8);
      acc[0][nt] = __builtin_amdgcn_mfma_f32_16x16x32_bf16(afrag[0], bfrag, acc[0][nt], 0, 0, 0);
      acc[1][nt] = __builtin_amdgcn_mfma_f32_16x16x32_bf16(afrag[1], bfrag, acc[1][nt], 0, 0, 0);
    }
  }
  // stats per o: lane's 8 acc elements (2 mt x 4 regs) all share o = nt*16+(lane&15)
#pragma unroll
  for (int nt = 0; nt < 8; ++nt) {
    float s = 0.f, q = 0.f, mx = -1e30f, mn = 1e30f;
#pragma unroll
    for (int mt = 0; mt < 2; ++mt)
#pragma unroll
      for (int r = 0; r < 4; ++r) {
        float a = acc[mt][nt][r];
        s += a; q = fmaf(a, a, q); mx = fmaxf(mx, a); mn = fminf(mn, a);
      }
    s += __shfl_xor(s, 16, 64); s += __shfl_xor(s, 32, 64);
    q += __shfl_xor(q, 16, 64); q += __shfl_xor(q, 32, 64);
    mx = fmaxf(mx, __shfl_xor(mx, 16, 64)); mx = fmaxf(mx, __shfl_xor(mx, 32, 64));
    mn = fminf(mn, __shfl_xor(mn, 16, 64)); mn = fminf(mn, __shfl_xor(mn, 32, 64));
    if (lane < 16) {
      int o = nt * 16 + lane;
      psum[o * G_ + g] = s; psq[o * G_ + g] = q;
      hmax[o * G_ + g] = mx; hmin[o * G_ + g] = mn;
    }
  }
}

// ---------------- pool: out[b,o,s] = relu(s2 * (s2>=0 ? max : min) + t2) ----------------
__global__ __launch_bounds__(256) void pool_kernel(const float* __restrict__ hmax,
    const float* __restrict__ hmin, const float* __restrict__ bnp2,
    float* __restrict__ out) {
  int i = blockIdx.x * 256 + threadIdx.x;   // 1,048,576 = (b*128+o)*512+s
  int s = i & 511;
  int o = (i >> 9) & 127;
  int b = i >> 16;
  int g = b * 512 + s;
  float scv = bnp2[2 * o], tf = bnp2[2 * o + 1];
  float v = (scv >= 0.f) ? hmax[o * G_ + g] : hmin[o * G_ + g];
  out[i] = fmaxf(fmaf(scv, v, tf), 0.f);
}

extern "C" void kernel_launch(void* const* d_in, const int* in_sizes, int n_in,
                              void* d_out, int out_size, void* d_ws, size_t ws_size,
                              hipStream_t stream) {
  const float* x      = (const float*)d_in[0];
  const float* coords = (const float*)d_in[1];
  const float* W1     = (const float*)d_in[2];
  const float* W2     = (const float*)d_in[3];
  const float* gamma1 = (const float*)d_in[4];
  const float* beta1  = (const float*)d_in[5];
  const float* gamma2 = (const float*)d_in[6];
  const float* beta2  = (const float*)d_in[7];
  float* out = (float*)d_out;
  char* ws = (char*)d_ws;
  ushort_t* h1T  = (ushort_t*)(ws);               // 67,108,864 B  (h1T[g][k][c] bf16)
  float* psum1 = (float*)(ws + 67108864);         // 4 MB each below
  float* psq1  = (float*)(ws + 71303168);
  float* psum2 = (float*)(ws + 75497472);
  float* psq2  = (float*)(ws + 79691776);
  float* hmax  = (float*)(ws + 83886080);
  float* hmin  = (float*)(ws + 88080384);
  float* Wt1   = (float*)(ws + 92274688);
  ushort_t* Bp2 = (ushort_t*)(ws + 92340224);     // 32 KB (W2 B-frag packed bf16)
  float* Wd1   = (float*)(ws + 92405760);
  float* bnp1  = (float*)(ws + 92438528);
  float* bnp2  = (float*)(ws + 92439552);
  int* fidx    = (int*)(ws + 92440576);
  int* gidx    = (int*)(ws + 92473344);           // end 93,521,920 B

  prep_kernel<<<64, 256, 0, stream>>>(W1, W2, Wt1, Wd1, Bp2);
  fps_kernel<<<16, 256, 0, stream>>>(coords, fidx, out);
  ball_kernel<<<2048, 256, 0, stream>>>(coords, fidx, gidx);
  gemm1_kernel<<<2048, 256, 0, stream>>>(x, fidx, gidx, Wt1, Wd1, h1T, psum1, psq1);
  bn_finalize<<<128, 256, 0, stream>>>(psum1, psq1, gamma1, beta1, bnp1);
  gemm2_kernel<<<2048, 256, 0, stream>>>(h1T, Bp2, bnp1, psum2, psq2, hmax, hmin);
  bn_finalize<<<128, 256, 0, stream>>>(psum2, psq2, gamma2, beta2, bnp2);
  pool_kernel<<<4096, 256, 0, stream>>>(hmax, hmin, bnp2, out + 24576);
}

// Round 5
// 387.194 us; speedup vs baseline: 2.0370x; 1.2033x over previous
//
#include <hip/hip_runtime.h>
#include <cstdint>

typedef unsigned int uint;
typedef unsigned short ushort_t;
typedef unsigned long long ull;
typedef __attribute__((ext_vector_type(8))) short bf16x8;
typedef __attribute__((ext_vector_type(4))) float f32x4;

#define B_   16
#define N_   2048
#define S_   512
#define G_   8192       // B_*S_
#define DIN  64
#define DOUT 128
#define K_   32
#define ATS  136        // gemm2 actT row stride (bf16)
#define ATS1 72         // gemm1 xgT row stride (bf16)

__device__ __forceinline__ uint bf16b(float f) {
  uint u = __float_as_uint(f);
  return (u + 0x7fffu + ((u >> 16) & 1u)) >> 16;
}
__device__ __forceinline__ float bf2f(uint b) { return __uint_as_float(b << 16); }

// u64 max with one DPP step applied to both halves (bc=1 zero-fill = identity for max)
template<int CTRL, int RM>
__device__ __forceinline__ ull dpp_max_step(ull x) {
  uint lo = (uint)x, hi = (uint)(x >> 32);
  uint nlo = (uint)__builtin_amdgcn_update_dpp((int)lo, (int)lo, CTRL, RM, 0xf, true);
  uint nhi = (uint)__builtin_amdgcn_update_dpp((int)hi, (int)hi, CTRL, RM, 0xf, true);
  ull y = ((ull)nhi << 32) | (ull)nlo;
  return x > y ? x : y;
}

// ---------------- FPS: one block/batch, 4 waves, 8 pts/thread, exact fp32 ----------
// Pre-barrier: lane63 writes 8B key only. Post-barrier: read 4 keys, issue all 4
// candidate float4 coord reads IN PARALLEL with the key-max resolve, cndmask-select.
// Reference scan emits PRE-update far (idx[0]==0) -> record at loop top.
__global__ __launch_bounds__(256) void fps_kernel(const float* __restrict__ coords,
                                                  int* __restrict__ fidx,
                                                  float* __restrict__ out_xyz) {
  int b = blockIdx.x;
  const float* cb = coords + (size_t)b * (N_ * 3);
  __shared__ float4 spt[N_];        // 32 KB: point coords for broadcast center fetch
  __shared__ ull    skey[2][4];
  __shared__ int    sfar[S_];
  int tid = threadIdx.x, wid = tid >> 6;
  float px[8], py[8], pz[8], dist[8];
  uint nidx[8];
  int j0 = tid * 8;
#pragma unroll
  for (int i = 0; i < 8; ++i) {
    float x3 = cb[3 * (j0 + i)], y3 = cb[3 * (j0 + i) + 1], z3 = cb[3 * (j0 + i) + 2];
    px[i] = x3; py[i] = y3; pz[i] = z3;
    spt[j0 + i] = make_float4(x3, y3, z3, 0.f);
    dist[i] = 1e10f;
    nidx[i] = ~(uint)(j0 + i);     // max(~j) == min(j): first-index tie-break
  }
  float cx = cb[0], cy = cb[1], cz = cb[2];
  uint far = 0;
  __syncthreads();
  for (int s = 0; s < S_; ++s) {
    if (tid == 0) sfar[s] = (int)far;          // PRE-update far (matches jax scan)
    ull best = 0;
#pragma unroll
    for (int i = 0; i < 8; ++i) {
      float dx = __fsub_rn(px[i], cx);
      float dy = __fsub_rn(py[i], cy);
      float dz = __fsub_rn(pz[i], cz);
      float d = __fadd_rn(__fadd_rn(__fmul_rn(dx, dx), __fmul_rn(dy, dy)), __fmul_rn(dz, dz));
      float nd = fminf(dist[i], d);
      dist[i] = nd;
      ull p = ((ull)__float_as_uint(nd) << 32) | (ull)nidx[i];
      best = best > p ? best : p;
    }
    // wave64 max-reduce, result lands in lane 63 (VALU-only DPP chain)
    best = dpp_max_step<0x111, 0xf>(best);   // row_shr:1
    best = dpp_max_step<0x112, 0xf>(best);   // row_shr:2
    best = dpp_max_step<0x114, 0xf>(best);   // row_shr:4
    best = dpp_max_step<0x118, 0xf>(best);   // row_shr:8
    best = dpp_max_step<0x142, 0xa>(best);   // row_bcast:15 -> rows 1,3
    best = dpp_max_step<0x143, 0xc>(best);   // row_bcast:31 -> rows 2,3
    int pb = s & 1;
    if ((tid & 63) == 63) skey[pb][wid] = best;
    __syncthreads();                          // lgkm-only: no global ops in flight
    ull k0 = skey[pb][0], k1 = skey[pb][1], k2 = skey[pb][2], k3 = skey[pb][3];
    uint jw0 = ~(uint)k0, jw1 = ~(uint)k1, jw2 = ~(uint)k2, jw3 = ~(uint)k3;
    float4 q0 = spt[jw0], q1 = spt[jw1], q2 = spt[jw2], q3 = spt[jw3]; // 4 parallel reads
    bool t01 = k0 > k1, t23 = k2 > k3;
    ull ka = t01 ? k0 : k1;   float4 qa = t01 ? q0 : q1;
    ull kb2 = t23 ? k2 : k3;  float4 qb = t23 ? q2 : q3;
    bool tw = ka > kb2;
    ull kw = tw ? ka : kb2;   float4 qw = tw ? qa : qb;
    far = ~(uint)kw;
    cx = qw.x; cy = qw.y; cz = qw.z;
  }
  __syncthreads();
  for (int s2 = tid; s2 < S_; s2 += 256) {
    int f = sfar[s2];
    fidx[b * S_ + s2] = f;
    float4 c4 = spt[f];
    int o = (b * S_ + s2) * 3;
    out_xyz[o] = c4.x; out_xyz[o + 1] = c4.y; out_xyz[o + 2] = c4.z;
  }
}

// ---------------- Ball query: one wave per centroid ----------------
__global__ __launch_bounds__(256) void ball_kernel(const float* __restrict__ coords,
                                                   const int* __restrict__ fidx,
                                                   int* __restrict__ gidx) {
  int lane = threadIdx.x & 63;
  int g = __builtin_amdgcn_readfirstlane(blockIdx.x * 4 + (threadIdx.x >> 6));
  int b = g >> 9;
  const float* cb = coords + (size_t)b * (N_ * 3);
  int nf = fidx[g];
  float cx = cb[3 * nf], cy = cb[3 * nf + 1], cz = cb[3 * nf + 2];
  int* out = gidx + g * K_;
  int cnt = 0, first = 0;
  bool hasfirst = false;
  for (int base = 0; base < N_; base += 64) {
    int j = base + lane;
    float dx = __fsub_rn(cb[3 * j], cx);
    float dy = __fsub_rn(cb[3 * j + 1], cy);
    float dz = __fsub_rn(cb[3 * j + 2], cz);
    float d = __fadd_rn(__fadd_rn(__fmul_rn(dx, dx), __fmul_rn(dy, dy)), __fmul_rn(dz, dz));
    bool in = (d <= 0.25f);     // kept iff sqr <= r^2 (ref excludes sqr > r^2)
    ull m = __ballot(in);
    if (in) {
      int pos = cnt + __popcll(m & ((1ull << lane) - 1ull));
      if (pos < K_) out[pos] = j;
    }
    if (!hasfirst && m) { first = base + (__ffsll((long long)m) - 1); hasfirst = true; }
    cnt += __popcll(m);
    if (cnt >= K_) break;
  }
  if (cnt < K_) {
    for (int p = cnt + lane; p < K_; p += 64) out[p] = first;
  }
}

// ---------------- prep: B-fragment packs for both GEMMs ----------------
// Bp2[i], i<16384: B2[c][o], c2=kc*32+(l>>4)*8+j, o2=nt*16+(l&15), kc=(i>>9)&3, nt=i>>11
// Bp1/Bpd[i], i<8192: same frag layout with kc=(i>>9)&1, nt=(i>>10)&7 (K=64)
__global__ __launch_bounds__(256) void prep_kernel(const float* __restrict__ W1,
                                                   const float* __restrict__ W2,
                                                   ushort_t* __restrict__ Bp1,
                                                   ushort_t* __restrict__ Bpd,
                                                   ushort_t* __restrict__ Bp2) {
  int i = blockIdx.x * 256 + threadIdx.x;   // 16384
  int j2 = i & 7, l = (i >> 3) & 63;
  {
    int kc = (i >> 9) & 3, nt = i >> 11;
    int o2 = nt * 16 + (l & 15);
    int c2 = kc * 32 + ((l >> 4) * 8) + j2;
    Bp2[i] = (ushort_t)bf16b(W2[o2 * 128 + c2]);
  }
  if (i < 8192) {
    int kc = (i >> 9) & 1, nt = (i >> 10) & 7;
    int o2 = nt * 16 + (l & 15);
    int c2 = kc * 32 + ((l >> 4) * 8) + j2;
    float wa = W1[o2 * 128 + c2];
    float wb = W1[o2 * 128 + 64 + c2];
    Bp1[i] = (ushort_t)bf16b(wa);
    Bpd[i] = (ushort_t)bf16b(wb - wa);
  }
}

// ---------------- GEMM1 (MFMA bf16): h1T[g][k][o] = W1a@xg + (W1b-W1a)@ctr ------
// CT layout D[m=k][n=o]; center term via MFMA (A-frag = broadcast ctr), copied mt0->mt1.
__global__ __launch_bounds__(256) void gemm1_kernel(const float* __restrict__ x,
    const int* __restrict__ fidx, const int* __restrict__ gidx,
    const ushort_t* __restrict__ Bp1, const ushort_t* __restrict__ Bpd,
    ushort_t* __restrict__ h1T, float* __restrict__ psum, float* __restrict__ psq) {
  __shared__ ushort_t xgT[4][32 * ATS1];
  __shared__ float sctr[4][DIN];
  int tid = threadIdx.x;
  int lane = tid & 63, wid = tid >> 6;
  int g = __builtin_amdgcn_readfirstlane(blockIdx.x * 4 + wid);
  int b = g >> 9;
  const float* xb = x + (size_t)b * (DIN * N_);
  int nf = fidx[g];
  sctr[wid][lane] = xb[(size_t)lane * N_ + nf];   // lane = c (0..63)
  int kk = lane & 31, ch = lane >> 5;
  int gik = gidx[g * K_ + kk];
  ushort_t* xw = xgT[wid];
#pragma unroll
  for (int cc = 0; cc < 32; ++cc) {
    int c = ch * 32 + cc;
    xw[kk * ATS1 + c] = (ushort_t)bf16b(xb[(size_t)c * N_ + gik]);
  }
  __syncthreads();
  int l15 = lane & 15, r8 = (lane >> 4) * 8;
  f32x4 acc[2][8];
#pragma unroll
  for (int nt = 0; nt < 8; ++nt) acc[0][nt] = (f32x4){0.f, 0.f, 0.f, 0.f};
  // center term: D[k][o] = sum_c ctr[c] * Bpd[c][o]  (rows identical)
#pragma unroll
  for (int kc = 0; kc < 2; ++kc) {
    union { bf16x8 v; ushort_t u[8]; } cu;
#pragma unroll
    for (int j = 0; j < 8; ++j) cu.u[j] = (ushort_t)bf16b(sctr[wid][kc * 32 + r8 + j]);
#pragma unroll
    for (int nt = 0; nt < 8; ++nt) {
      bf16x8 bf = *(const bf16x8*)(Bpd + ((nt * 2 + kc) * 64 + lane) * 8);
      acc[0][nt] = __builtin_amdgcn_mfma_f32_16x16x32_bf16(cu.v, bf, acc[0][nt], 0, 0, 0);
    }
  }
#pragma unroll
  for (int nt = 0; nt < 8; ++nt) acc[1][nt] = acc[0][nt];
  // grouped term
#pragma unroll
  for (int kc = 0; kc < 2; ++kc) {
    bf16x8 afrag[2];
#pragma unroll
    for (int mt = 0; mt < 2; ++mt)
      afrag[mt] = *(const bf16x8*)(xw + (mt * 16 + l15) * ATS1 + kc * 32 + r8);
#pragma unroll
    for (int nt = 0; nt < 8; ++nt) {
      bf16x8 bf = *(const bf16x8*)(Bp1 + ((nt * 2 + kc) * 64 + lane) * 8);
      acc[0][nt] = __builtin_amdgcn_mfma_f32_16x16x32_bf16(afrag[0], bf, acc[0][nt], 0, 0, 0);
      acc[1][nt] = __builtin_amdgcn_mfma_f32_16x16x32_bf16(afrag[1], bf, acc[1][nt], 0, 0, 0);
    }
  }
  // stats per o (lane's 8 acc vals share o = nt*16+l15)
#pragma unroll
  for (int nt = 0; nt < 8; ++nt) {
    float s = 0.f, q = 0.f;
#pragma unroll
    for (int mt = 0; mt < 2; ++mt)
#pragma unroll
      for (int r = 0; r < 4; ++r) { float a = acc[mt][nt][r]; s += a; q = fmaf(a, a, q); }
    s += __shfl_xor(s, 16, 64); s += __shfl_xor(s, 32, 64);
    q += __shfl_xor(q, 16, 64); q += __shfl_xor(q, 32, 64);
    if (lane < 16) {
      int o = nt * 16 + lane;
      psum[o * G_ + g] = s; psq[o * G_ + g] = q;
    }
  }
  // transposed store h1T[g][k][o], k = mt*16+(lane>>4)*4+r, o = nt*16+l15
#pragma unroll
  for (int mt = 0; mt < 2; ++mt)
#pragma unroll
    for (int r = 0; r < 4; ++r) {
      int k = mt * 16 + (lane >> 4) * 4 + r;
      ushort_t* dst = h1T + (size_t)g * 4096 + k * 128 + l15;
#pragma unroll
      for (int nt = 0; nt < 8; ++nt)
        dst[nt * 16] = (ushort_t)bf16b(acc[mt][nt][r]);
    }
}

// ---------------- BN finalize: per-channel mean/var -> scale/shift ----------------
__global__ __launch_bounds__(256) void bn_finalize(const float* __restrict__ psum,
    const float* __restrict__ psq, const float* __restrict__ gamma,
    const float* __restrict__ beta, float* __restrict__ bnp) {
  int o = blockIdx.x, tid = threadIdx.x;
  double s = 0.0, q = 0.0;
  for (int g = tid; g < G_; g += 256) { s += (double)psum[o * G_ + g]; q += (double)psq[o * G_ + g]; }
  __shared__ double ss[256], qq[256];
  ss[tid] = s; qq[tid] = q; __syncthreads();
  for (int off = 128; off > 0; off >>= 1) {
    if (tid < off) { ss[tid] += ss[tid + off]; qq[tid] += qq[tid + off]; }
    __syncthreads();
  }
  if (tid == 0) {
    double n = 262144.0;
    double mean = ss[0] / n, var = qq[0] / n - mean * mean;
    float scv = (float)((double)gamma[o] / sqrt(var + 1e-5));
    bnp[2 * o] = scv;
    bnp[2 * o + 1] = (float)((double)beta[o] - mean * (double)scv);
  }
}

// ---------------- GEMM2 (MFMA bf16): CT layout D[k][o], per-(g,o) stats ----------
__global__ __launch_bounds__(256) void gemm2_kernel(const ushort_t* __restrict__ h1T,
    const ushort_t* __restrict__ Bp2, const float* __restrict__ bnp1,
    float* __restrict__ psum, float* __restrict__ psq,
    float* __restrict__ hmax, float* __restrict__ hmin) {
  __shared__ ushort_t actT[4][32 * ATS];
  int tid = threadIdx.x;
  int lane = tid & 63, wid = tid >> 6;
  int g = __builtin_amdgcn_readfirstlane(blockIdx.x * 4 + wid);
  ushort_t* aw = actT[wid];
  int c0 = (lane & 15) * 8;
  float s1[8], t1[8];
#pragma unroll
  for (int jj = 0; jj < 8; ++jj) { s1[jj] = bnp1[2 * (c0 + jj)]; t1[jj] = bnp1[2 * (c0 + jj) + 1]; }
  const uint4* src = (const uint4*)(h1T + (size_t)g * 4096);
#pragma unroll
  for (int t = 0; t < 8; ++t) {
    int idx = t * 64 + lane;           // uint4 index; k = idx>>4, c-block = (idx&15)*8
    uint4 v = src[idx];
    int k = idx >> 4;
    uint w[4] = {v.x, v.y, v.z, v.w};
    uint o4[4];
#pragma unroll
    for (int p2 = 0; p2 < 4; ++p2) {
      float a0 = fmaxf(fmaf(bf2f(w[p2] & 0xffffu), s1[2 * p2], t1[2 * p2]), 0.f);
      float a1 = fmaxf(fmaf(bf2f(w[p2] >> 16), s1[2 * p2 + 1], t1[2 * p2 + 1]), 0.f);
      o4[p2] = (bf16b(a1) << 16) | bf16b(a0);
    }
    *(uint4*)(aw + k * ATS + c0) = make_uint4(o4[0], o4[1], o4[2], o4[3]);
  }
  __syncthreads();
  f32x4 acc[2][8];
#pragma unroll
  for (int mt = 0; mt < 2; ++mt)
#pragma unroll
    for (int nt = 0; nt < 8; ++nt) acc[mt][nt] = (f32x4){0.f, 0.f, 0.f, 0.f};
#pragma unroll
  for (int kc = 0; kc < 4; ++kc) {
    bf16x8 afrag[2];
#pragma unroll
    for (int mt = 0; mt < 2; ++mt)
      afrag[mt] = *(const bf16x8*)(aw + (mt * 16 + (lane & 15)) * ATS + kc * 32 + (lane >> 4) * 8);
#pragma unroll
    for (int nt = 0; nt < 8; ++nt) {
      bf16x8 bfrag = *(const bf16x8*)(Bp2 + ((nt * 4 + kc) * 64 + lane) * 8);
      acc[0][nt] = __builtin_amdgcn_mfma_f32_16x16x32_bf16(afrag[0], bfrag, acc[0][nt], 0, 0, 0);
      acc[1][nt] = __builtin_amdgcn_mfma_f32_16x16x32_bf16(afrag[1], bfrag, acc[1][nt], 0, 0, 0);
    }
  }
#pragma unroll
  for (int nt = 0; nt < 8; ++nt) {
    float s = 0.f, q = 0.f, mx = -1e30f, mn = 1e30f;
#pragma unroll
    for (int mt = 0; mt < 2; ++mt)
#pragma unroll
      for (int r = 0; r < 4; ++r) {
        float a = acc[mt][nt][r];
        s += a; q = fmaf(a, a, q); mx = fmaxf(mx, a); mn = fminf(mn, a);
      }
    s += __shfl_xor(s, 16, 64); s += __shfl_xor(s, 32, 64);
    q += __shfl_xor(q, 16, 64); q += __shfl_xor(q, 32, 64);
    mx = fmaxf(mx, __shfl_xor(mx, 16, 64)); mx = fmaxf(mx, __shfl_xor(mx, 32, 64));
    mn = fminf(mn, __shfl_xor(mn, 16, 64)); mn = fminf(mn, __shfl_xor(mn, 32, 64));
    if (lane < 16) {
      int o = nt * 16 + lane;
      psum[o * G_ + g] = s; psq[o * G_ + g] = q;
      hmax[o * G_ + g] = mx; hmin[o * G_ + g] = mn;
    }
  }
}

// ---------------- pool: out[b,o,s] = relu(s2 * (s2>=0 ? max : min) + t2) ----------------
__global__ __launch_bounds__(256) void pool_kernel(const float* __restrict__ hmax,
    const float* __restrict__ hmin, const float* __restrict__ bnp2,
    float* __restrict__ out) {
  int i = blockIdx.x * 256 + threadIdx.x;   // 1,048,576 = (b*128+o)*512+s
  int s = i & 511;
  int o = (i >> 9) & 127;
  int b = i >> 16;
  int g = b * 512 + s;
  float scv = bnp2[2 * o], tf = bnp2[2 * o + 1];
  float v = (scv >= 0.f) ? hmax[o * G_ + g] : hmin[o * G_ + g];
  out[i] = fmaxf(fmaf(scv, v, tf), 0.f);
}

extern "C" void kernel_launch(void* const* d_in, const int* in_sizes, int n_in,
                              void* d_out, int out_size, void* d_ws, size_t ws_size,
                              hipStream_t stream) {
  const float* x      = (const float*)d_in[0];
  const float* coords = (const float*)d_in[1];
  const float* W1     = (const float*)d_in[2];
  const float* W2     = (const float*)d_in[3];
  const float* gamma1 = (const float*)d_in[4];
  const float* beta1  = (const float*)d_in[5];
  const float* gamma2 = (const float*)d_in[6];
  const float* beta2  = (const float*)d_in[7];
  float* out = (float*)d_out;
  char* ws = (char*)d_ws;
  ushort_t* h1T  = (ushort_t*)(ws);               // 67,108,864 B  (h1T[g][k][o] bf16)
  float* psum1 = (float*)(ws + 67108864);         // 4 MB each below
  float* psq1  = (float*)(ws + 71303168);
  float* psum2 = (float*)(ws + 75497472);
  float* psq2  = (float*)(ws + 79691776);
  float* hmax  = (float*)(ws + 83886080);
  float* hmin  = (float*)(ws + 88080384);
  ushort_t* Bp1 = (ushort_t*)(ws + 92274688);     // 16 KB
  ushort_t* Bpd = (ushort_t*)(ws + 92291072);     // 16 KB
  ushort_t* Bp2 = (ushort_t*)(ws + 92307456);     // 32 KB
  float* bnp1  = (float*)(ws + 92340224);
  float* bnp2  = (float*)(ws + 92341248);
  int* fidx    = (int*)(ws + 92342272);           // 32 KB
  int* gidx    = (int*)(ws + 92375040);           // 1 MB, end 93,423,616 B

  prep_kernel<<<64, 256, 0, stream>>>(W1, W2, Bp1, Bpd, Bp2);
  fps_kernel<<<16, 256, 0, stream>>>(coords, fidx, out);
  ball_kernel<<<2048, 256, 0, stream>>>(coords, fidx, gidx);
  gemm1_kernel<<<2048, 256, 0, stream>>>(x, fidx, gidx, Bp1, Bpd, h1T, psum1, psq1);
  bn_finalize<<<128, 256, 0, stream>>>(psum1, psq1, gamma1, beta1, bnp1);
  gemm2_kernel<<<2048, 256, 0, stream>>>(h1T, Bp2, bnp1, psum2, psq2, hmax, hmin);
  bn_finalize<<<128, 256, 0, stream>>>(psum2, psq2, gamma2, beta2, bnp2);
  pool_kernel<<<4096, 256, 0, stream>>>(hmax, hmin, bnp2, out + 24576);
}